// Round 2
// baseline (43.709 us; speedup 1.0000x reference)
//
#include <hip/hip_runtime.h>

// Problem constants (from reference)
#define BB 8
#define CC 512
#define NN 4096   // H*W = 64*64
#define HID 24

// ---------------------------------------------------------------------------
// Kernel 1: g[b,c] = mean_hw(rgb) + mean_hw(chm) + 2/N
// (attention branch == constant 2/N: softmax over spatial axis sums to 1,
//  GAP averages exactly that axis)
//
// One WAVE per channel. 1024 blocks x 256 threads = 4096 waves = 4 blocks/CU.
// Each lane: 16 float4 from rgb + 16 float4 from chm (512 B/lane), loaded in
// two fully-unrolled batches of 16 outstanding loads so the memory pipe stays
// saturated. No LDS, no barrier; wave-level butterfly reduce only.
// ---------------------------------------------------------------------------
__global__ __launch_bounds__(256, 4) void gap_kernel(
    const float* __restrict__ rgb,
    const float* __restrict__ chm,
    float* __restrict__ g)
{
    const int ch   = blockIdx.x * 4 + (threadIdx.x >> 6);   // 0..4095 (b*C+c)
    const int lane = threadIdx.x & 63;

    const float4* r4 = reinterpret_cast<const float4*>(rgb) + (size_t)ch * (NN / 4);
    const float4* c4 = reinterpret_cast<const float4*>(chm) + (size_t)ch * (NN / 4);

    float s0 = 0.f, s1 = 0.f, s2 = 0.f, s3 = 0.f;

    #pragma unroll
    for (int half = 0; half < 2; ++half) {
        float4 a[8], b[8];
        // issue 16 independent loads before consuming any result
        #pragma unroll
        for (int i = 0; i < 8; ++i) a[i] = r4[lane + (half * 8 + i) * 64];
        #pragma unroll
        for (int i = 0; i < 8; ++i) b[i] = c4[lane + (half * 8 + i) * 64];
        #pragma unroll
        for (int i = 0; i < 8; ++i) {
            s0 += a[i].x + b[i].x;
            s1 += a[i].y + b[i].y;
            s2 += a[i].z + b[i].z;
            s3 += a[i].w + b[i].w;
        }
    }
    float s = (s0 + s1) + (s2 + s3);

    #pragma unroll
    for (int off = 32; off; off >>= 1)
        s += __shfl_down(s, off, 64);

    if (lane == 0)
        g[ch] = s * (1.0f / NN) + 2.0f / NN;
}

// ---------------------------------------------------------------------------
// Kernel 2: tiny MLP.  h1 = relu(g @ w1^T) [8,24]; out = sigmoid(h1 @ w2^T) [8]
// ---------------------------------------------------------------------------
__global__ __launch_bounds__(256) void mlp_kernel(
    const float* __restrict__ g,
    const float* __restrict__ w1,   // [24, 512] row-major
    const float* __restrict__ w2,   // [24]
    float* __restrict__ out)        // [8]
{
    __shared__ float gs[BB * CC];   // 16 KB
    __shared__ float h1[BB][HID];

    const int t = threadIdx.x;
    for (int i = t; i < BB * CC; i += 256) gs[i] = g[i];
    __syncthreads();

    if (t < BB * HID) {
        const int b = t / HID, j = t % HID;
        const float* wrow = w1 + j * CC;
        const float* grow = gs + b * CC;
        float acc = 0.0f;
        #pragma unroll 8
        for (int c = 0; c < CC; ++c) acc = fmaf(grow[c], wrow[c], acc);
        h1[b][j] = acc > 0.0f ? acc : 0.0f;
    }
    __syncthreads();

    if (t < BB) {
        float acc = 0.0f;
        #pragma unroll
        for (int j = 0; j < HID; ++j) acc = fmaf(h1[t][j], w2[j], acc);
        out[t] = 1.0f / (1.0f + expf(-acc));
    }
}

extern "C" void kernel_launch(void* const* d_in, const int* in_sizes, int n_in,
                              void* d_out, int out_size, void* d_ws, size_t ws_size,
                              hipStream_t stream) {
    const float* rgb = (const float*)d_in[0];
    const float* chm = (const float*)d_in[1];
    // d_in[2..5] = qkv weights/biases: provably unused (softmax-mean identity)
    const float* w1  = (const float*)d_in[6];   // [24,512]
    const float* w2  = (const float*)d_in[7];   // [1,24]
    float* out = (float*)d_out;                 // [8]

    float* g = (float*)d_ws;                    // 4096 floats = 16 KB scratch

    gap_kernel<<<(BB * CC) / 4, 256, 0, stream>>>(rgb, chm, g);
    mlp_kernel<<<1, 256, 0, stream>>>(g, w1, w2, out);
}

// Round 3
// 41.710 us; speedup vs baseline: 1.0479x; 1.0479x over previous
//
#include <hip/hip_runtime.h>

// Problem constants (from reference)
#define BB 8
#define CC 512
#define NN 4096   // H*W = 64*64
#define HID 24

// ---------------------------------------------------------------------------
// Kernel 1: g[b,c] = mean_hw(rgb) + mean_hw(chm) + 2/N
// (attention branch == constant 2/N: softmax over spatial axis sums to 1,
//  GAP averages exactly that axis)
//
// Anti-bank-camping version. 2048 blocks x 256 threads; each block owns 2
// channels, each channel split across 2 waves (8 KB per wave per tensor).
// Each wave reads its 8 slots of 1 KB in a channel-dependent rotated ORDER,
// so instantaneous accesses across waves are spread over all 16 x 1KB phases
// of the 16 KB channel stride instead of camping on phase 0.
// ---------------------------------------------------------------------------
__global__ __launch_bounds__(256, 4) void gap_kernel(
    const float* __restrict__ rgb,
    const float* __restrict__ chm,
    float* __restrict__ g)
{
    const int wid  = threadIdx.x >> 6;                    // 0..3
    const int lane = threadIdx.x & 63;
    const int ch   = blockIdx.x * 2 + (wid >> 1);         // 0..4095
    const int half = wid & 1;                             // which 8 KB half

    const int phr = (ch * 3 + half * 5) & 7;              // rgb phase
    const int phc = (phr + 3) & 7;                        // chm phase

    const float4* r4 = reinterpret_cast<const float4*>(rgb)
                     + (size_t)ch * (NN / 4) + half * 512;
    const float4* c4 = reinterpret_cast<const float4*>(chm)
                     + (size_t)ch * (NN / 4) + half * 512;

    float4 a[8], b[8];
    #pragma unroll
    for (int j = 0; j < 8; ++j) a[j] = r4[lane + (((j + phr) & 7) << 6)];
    #pragma unroll
    for (int j = 0; j < 8; ++j) b[j] = c4[lane + (((j + phc) & 7) << 6)];

    float s0 = 0.f, s1 = 0.f, s2 = 0.f, s3 = 0.f;
    #pragma unroll
    for (int j = 0; j < 8; ++j) {
        s0 += a[j].x + b[j].x;
        s1 += a[j].y + b[j].y;
        s2 += a[j].z + b[j].z;
        s3 += a[j].w + b[j].w;
    }
    float s = (s0 + s1) + (s2 + s3);

    #pragma unroll
    for (int off = 32; off; off >>= 1)
        s += __shfl_down(s, off, 64);

    __shared__ float part[4];
    if (lane == 0) part[wid] = s;
    __syncthreads();
    if (lane == 0 && half == 0) {                         // wid 0 and 2
        float tot = part[wid] + part[wid + 1];
        g[ch] = tot * (1.0f / NN) + 2.0f / NN;
    }
}

// ---------------------------------------------------------------------------
// Kernel 2: tiny MLP.  h1 = relu(g @ w1^T) [8,24]; out = sigmoid(h1 @ w2^T) [8]
// ---------------------------------------------------------------------------
__global__ __launch_bounds__(256) void mlp_kernel(
    const float* __restrict__ g,
    const float* __restrict__ w1,   // [24, 512] row-major
    const float* __restrict__ w2,   // [24]
    float* __restrict__ out)        // [8]
{
    __shared__ float gs[BB * CC];   // 16 KB
    __shared__ float h1[BB][HID];

    const int t = threadIdx.x;
    for (int i = t; i < BB * CC; i += 256) gs[i] = g[i];
    __syncthreads();

    if (t < BB * HID) {
        const int b = t / HID, j = t % HID;
        const float* wrow = w1 + j * CC;
        const float* grow = gs + b * CC;
        float acc = 0.0f;
        #pragma unroll 8
        for (int c = 0; c < CC; ++c) acc = fmaf(grow[c], wrow[c], acc);
        h1[b][j] = acc > 0.0f ? acc : 0.0f;
    }
    __syncthreads();

    if (t < BB) {
        float acc = 0.0f;
        #pragma unroll
        for (int j = 0; j < HID; ++j) acc = fmaf(h1[t][j], w2[j], acc);
        out[t] = 1.0f / (1.0f + expf(-acc));
    }
}

extern "C" void kernel_launch(void* const* d_in, const int* in_sizes, int n_in,
                              void* d_out, int out_size, void* d_ws, size_t ws_size,
                              hipStream_t stream) {
    const float* rgb = (const float*)d_in[0];
    const float* chm = (const float*)d_in[1];
    // d_in[2..5] = qkv weights/biases: provably unused (softmax-mean identity)
    const float* w1  = (const float*)d_in[6];   // [24,512]
    const float* w2  = (const float*)d_in[7];   // [1,24]
    float* out = (float*)d_out;                 // [8]

    float* g = (float*)d_ws;                    // 4096 floats = 16 KB scratch

    gap_kernel<<<(BB * CC) / 2, 256, 0, stream>>>(rgb, chm, g);
    mlp_kernel<<<1, 256, 0, stream>>>(g, w1, w2, out);
}